// Round 8
// baseline (441.590 us; speedup 1.0000x reference)
//
#include <hip/hip_runtime.h>
#include <hip/hip_bf16.h>

typedef __bf16 bf16;
typedef __bf16 bf16x8 __attribute__((ext_vector_type(8)));
typedef __bf16 bf16x4 __attribute__((ext_vector_type(4)));
typedef float  f32x4v __attribute__((ext_vector_type(4)));

#define MFMA16(a, b, c) __builtin_amdgcn_mfma_f32_16x16x32_bf16((a), (b), (c), 0, 0, 0)

static constexpr int D_MODEL = 1024;
static constexpr int NH      = 16;
static constexpr int DK      = 64;
static constexpr int BATCH   = 4;
static constexpr int SEQ     = 2048;
static constexpr float CLOG  = 0.125f * 1.4426950408889634f;  // 1/sqrt(dk) * log2(e)

// async global->LDS, 16B per lane; LDS dest = wave-uniform base + lane*16
__device__ __forceinline__ void glds16(const void* g, void* l) {
    __builtin_amdgcn_global_load_lds((const __attribute__((address_space(1))) void*)g,
                                     (__attribute__((address_space(3))) void*)l, 16, 0, 0);
}

// ---------------------------------------------------------------------------
// fp32 -> bf16 bulk convert, 7 tensors + mask prep in ONE launch (y selects).
// Mask slice (y==7): int32 [S][S] -> bf16 ADDITIVE bias, columns permuted
// within each 64-group to pos(s) = quad(s)*16 + n(s)*4 + r(s) where
// s = 16n + 4quad + r (matches the attn PV k-axis).  bias = 0 or -16384
// (exact in bf16; exp2 underflows to exactly 0, matching the -1e9 ref).
// ---------------------------------------------------------------------------
struct CvtArgs {
    const float* s[7];
    bf16* d[7];
    int n[7];
    const int* mask;
    bf16* Mr;
};

__global__ __launch_bounds__(256) void cvt8(CvtArgs a) {
    const int which = blockIdx.y;
    const int i = (blockIdx.x * 256 + threadIdx.x) * 8;
    if (which == 7) {  // mask prep, 8 outputs/thread (same row & 64-group)
        if (i >= SEQ * SEQ) return;
        const int row = i >> 11, j0 = i & 2047;
        const int g = j0 >> 6;
        bf16x8 o;
#pragma unroll
        for (int t = 0; t < 8; ++t) {
            const int idx = (j0 + t) & 63;  // = pos; invert the permutation
            const int incol =
                (g << 6) + (((idx >> 2) & 3) << 4) + ((idx >> 4) << 2) + (idx & 3);
            o[t] = a.mask[row * 2048 + incol] ? (bf16)0.0f : (bf16)-16384.0f;
        }
        *(bf16x8*)(a.Mr + i) = o;
        return;
    }
    if (i >= a.n[which]) return;
    const float4 v0 = *(const float4*)(a.s[which] + i);
    const float4 v1 = *(const float4*)(a.s[which] + i + 4);
    bf16x8 o = {(bf16)v0.x, (bf16)v0.y, (bf16)v0.z, (bf16)v0.w,
                (bf16)v1.x, (bf16)v1.y, (bf16)v1.z, (bf16)v1.w};
    *(bf16x8*)(a.d[which] + i) = o;
}

// ---------------------------------------------------------------------------
// Fused Q/K/V projection GEMMs: one launch, blockIdx.y selects tensor.
// C = (A @ W^T + bias) * scale.  128x128 tile, BK=32, glds16 staging,
// m97-style K-loop, 4 waves of 64x64.  XCD panel-clustered swizzle on x
// (same m-panel -> same XCD -> A-panel fetched into one L2 once).
// y=0: Q, scale=CLOG (pre-scales scores so attn exp2 needs no fma);
// y=1: K, scale=1    — both stored head-major bf16 [b][h][s][dk];
// y=2: V, stored as V^T [b][h][dk][s] with s permuted per 64-group:
//      pos(s) = quad*16 + n*4 + r  (matches mask / attn PV k-axis).
// ---------------------------------------------------------------------------
struct G3 {
    const bf16* A[3];
    const bf16* W[3];
    const float* bias[3];
    bf16* out[3];
};

__global__ __launch_bounds__(256) void gemm_qkv(G3 g) {
    __shared__ bf16 Als[128 * 32];  // packed row-major, stride 32 bf16 (64 B)
    __shared__ bf16 Bls[128 * 32];

    const int which = blockIdx.y;
    const bf16* __restrict__ A   = g.A[which];
    const bf16* __restrict__ W   = g.W[which];
    const float* __restrict__ bias = g.bias[which];
    const float scale = (which == 0) ? CLOG : 1.0f;

    const int tid  = threadIdx.x;
    const int wave = tid >> 6;
    const int lane = tid & 63;
    const int l15  = lane & 15;
    const int quad = lane >> 4;
    // XCD swizzle: L bits [2:0]=a, [5:3]=b, [8:6]=c.  m-tile = a + 8c (64),
    // n-tile = b (8).  Same m-tile => same a => same XCD (hw: linear%8;
    // grid x-size 512 is a multiple of 8 so each y-slice maps identically).
    const int L    = blockIdx.x;
    const int m0   = ((L & 7) | ((L >> 6) << 3)) * 128;
    const int n0   = ((L >> 3) & 7) * 128;
    const int wm   = (wave >> 1) * 64;
    const int wn   = (wave & 1) * 64;

    f32x4v acc[4][4];
#pragma unroll
    for (int i = 0; i < 4; ++i)
#pragma unroll
        for (int j = 0; j < 4; ++j) acc[i][j] = (f32x4v){0.f, 0.f, 0.f, 0.f};

    // staging map: slot = p*256 + wave*64 + lane; row = slot>>2, chunk = slot&3
    const int r_a    = wave * 16 + (lane >> 2);
    const int c_a    = (lane & 3) * 8;
    const int ldsoff = wave * 512;  // elements; + p*2048

    for (int k0 = 0; k0 < 1024; k0 += 32) {
        __syncthreads();
#pragma unroll
        for (int p = 0; p < 2; ++p) {
            const int row = p * 64 + r_a;
            glds16(A + (size_t)(m0 + row) * 1024 + k0 + c_a, &Als[p * 2048 + ldsoff]);
            glds16(W + (size_t)(n0 + row) * 1024 + k0 + c_a, &Bls[p * 2048 + ldsoff]);
        }
        __syncthreads();

        bf16x8 af[4], bfr[4];
#pragma unroll
        for (int i = 0; i < 4; ++i)
            af[i] = *(const bf16x8*)(&Als[(wm + i * 16 + l15) * 32 + quad * 8]);
#pragma unroll
        for (int j = 0; j < 4; ++j)
            bfr[j] = *(const bf16x8*)(&Bls[(wn + j * 16 + l15) * 32 + quad * 8]);
#pragma unroll
        for (int i = 0; i < 4; ++i)
#pragma unroll
            for (int j = 0; j < 4; ++j) acc[i][j] = MFMA16(af[i], bfr[j], acc[i][j]);
    }

    // epilogue: C/D layout col = lane&15, row = quad*4 + reg
    bf16* out = g.out[which];
#pragma unroll
    for (int j = 0; j < 4; ++j) {
        const int col = n0 + wn + j * 16 + l15;
        const float bs_s = bias[col] * scale;
        const int h = col >> 6, dk = col & 63;
        if (which == 2) {
            // V^T: logical s-offset o = i*16 + quad*4 + reg -> pos = quad*16+i*4+reg
            // so for fixed i the 4 reg-values are contiguous: bf16x4 store.
            const int sg = m0 + wm;               // 64-aligned
            const int bb = sg >> 11, sb = sg & 2047;
            const size_t rowbase = ((size_t)((bb * NH + h) * 64 + dk)) * SEQ + sb;
#pragma unroll
            for (int i = 0; i < 4; ++i) {
                bf16x4 v = {(bf16)(acc[i][j][0] + bs_s), (bf16)(acc[i][j][1] + bs_s),
                            (bf16)(acc[i][j][2] + bs_s), (bf16)(acc[i][j][3] + bs_s)};
                *(bf16x4*)(&out[rowbase + quad * 16 + i * 4]) = v;
            }
        } else {  // Q/K head-major, optionally pre-scaled
#pragma unroll
            for (int i = 0; i < 4; ++i) {
                const int r4 = m0 + wm + i * 16 + quad * 4;
                const int b = r4 >> 11, sb = r4 & 2047;
#pragma unroll
                for (int reg = 0; reg < 4; ++reg)
                    out[((size_t)(b * NH + h) * SEQ + sb + reg) * 64 + dk] =
                        (bf16)fmaf(acc[i][j][reg], scale, bs_s);
            }
        }
    }
}

// ---------------------------------------------------------------------------
// Final output GEMM: fp32 out = A @ Wo^T + bo.  Same structure as gemm_qkv.
// ---------------------------------------------------------------------------
__global__ __launch_bounds__(256) void gemm_o(const bf16* __restrict__ A,
                                              const bf16* __restrict__ W,
                                              const float* __restrict__ bias,
                                              float* __restrict__ out) {
    __shared__ bf16 Als[128 * 32];
    __shared__ bf16 Bls[128 * 32];

    const int tid  = threadIdx.x;
    const int wave = tid >> 6;
    const int lane = tid & 63;
    const int l15  = lane & 15;
    const int quad = lane >> 4;
    const int L    = blockIdx.x;
    const int m0   = ((L & 7) | ((L >> 6) << 3)) * 128;
    const int n0   = ((L >> 3) & 7) * 128;
    const int wm   = (wave >> 1) * 64;
    const int wn   = (wave & 1) * 64;

    f32x4v acc[4][4];
#pragma unroll
    for (int i = 0; i < 4; ++i)
#pragma unroll
        for (int j = 0; j < 4; ++j) acc[i][j] = (f32x4v){0.f, 0.f, 0.f, 0.f};

    const int r_a    = wave * 16 + (lane >> 2);
    const int c_a    = (lane & 3) * 8;
    const int ldsoff = wave * 512;

    for (int k0 = 0; k0 < 1024; k0 += 32) {
        __syncthreads();
#pragma unroll
        for (int p = 0; p < 2; ++p) {
            const int row = p * 64 + r_a;
            glds16(A + (size_t)(m0 + row) * 1024 + k0 + c_a, &Als[p * 2048 + ldsoff]);
            glds16(W + (size_t)(n0 + row) * 1024 + k0 + c_a, &Bls[p * 2048 + ldsoff]);
        }
        __syncthreads();

        bf16x8 af[4], bfr[4];
#pragma unroll
        for (int i = 0; i < 4; ++i)
            af[i] = *(const bf16x8*)(&Als[(wm + i * 16 + l15) * 32 + quad * 8]);
#pragma unroll
        for (int j = 0; j < 4; ++j)
            bfr[j] = *(const bf16x8*)(&Bls[(wn + j * 16 + l15) * 32 + quad * 8]);
#pragma unroll
        for (int i = 0; i < 4; ++i)
#pragma unroll
            for (int j = 0; j < 4; ++j) acc[i][j] = MFMA16(af[i], bfr[j], acc[i][j]);
    }

#pragma unroll
    for (int j = 0; j < 4; ++j) {
        const int col = n0 + wn + j * 16 + l15;
        const float bs = bias[col];
#pragma unroll
        for (int i = 0; i < 4; ++i) {
            const int r4 = m0 + wm + i * 16 + quad * 4;
#pragma unroll
            for (int reg = 0; reg < 4; ++reg)
                out[(size_t)(r4 + reg) * 1024 + col] = acc[i][j][reg] + bs;
        }
    }
}

// ---------------------------------------------------------------------------
// Flash attention, fixed-max softmax.  Q PRE-SCALED by CLOG; QK^T accumulator
// SEEDED with the bf16 mask bias (0/-16384): e = exp2(sv) directly.  Masked
// terms are exactly 0 (underflow), matching the -1e9 ref.
//
// SWAPPED QK^T: mfma(K, Q) puts q = l15 -> each lane's scores belong to its
// own q-row = the PV A-frag layout; P never touches LDS.  The induced
// k-permutation pos(s)=quad*16+n*4+r is baked into V^T and the mask.
//
// 8-wave (512-thread) blocks, 32 q-rows/wave (rb=2): waves/CU 8 -> 16 at
// IDENTICAL staging traffic and barrier count per CU vs the 4-wave version.
//
// ROUND-7 FIX (resubmitted; round-7 bench was an infra failure): round 6's
// __launch_bounds__(512,4) made the backend target an 8-waves/EU register
// budget (VGPR=64) and SPILL ~40 regs to scratch (WRITE_SIZE 16->45 MB, the
// whole regression).  (512,2) sets the floor at 2 waves/EU (256-VGPR
// budget): the allocator takes what it needs (~100, no spill), and since
// that lands <=128 the HARDWARE still runs 4 waves/EU.
// Single-barrier double-buffered staging (stage t+1, compute t).
// Row sums via ones-MFMA.
// ---------------------------------------------------------------------------
__global__ __launch_bounds__(512, 2) void attn_kernel(const bf16* __restrict__ Qh,
                                                      const bf16* __restrict__ Kh,
                                                      const bf16* __restrict__ Vtg,
                                                      const bf16* __restrict__ Mr,
                                                      bf16* __restrict__ Xout) {
    __shared__ bf16 Kls[2][4096];    // per buf: 8 chunks x 64 keys x 8 bf16
    __shared__ bf16 Vls[2][4096];    // per buf: 8 chunks x 64 d    x 8 bf16

    const int tid  = threadIdx.x;
    const int wave = tid >> 6;       // 0..7
    const int lane = tid & 63;
    const int l15  = lane & 15;
    const int quad = lane >> 4;
    const int bh   = blockIdx.x;
    const int q0   = blockIdx.y * 256;

    const size_t base = (size_t)bh * SEQ * DK;
    const bf16* Q  = Qh + base;
    const bf16* K  = Kh + base;
    const bf16* Vg = Vtg + base;  // [64][SEQ], s permuted per 64-group

    const int qw = q0 + wave * 32;   // 32 q-rows per wave
    bf16x8 aq[2][2];
#pragma unroll
    for (int rb = 0; rb < 2; ++rb)
#pragma unroll
        for (int kk = 0; kk < 2; ++kk)
            aq[rb][kk] = *(const bf16x8*)(Q + (size_t)(qw + rb * 16 + l15) * 64 +
                                          kk * 32 + quad * 8);

    bf16x8 ones;
#pragma unroll
    for (int t = 0; t < 8; ++t) ones[t] = (bf16)1.0f;

    f32x4v acc[2][4];  // [rb][nt] PV accumulators
    f32x4v sacc[2];    // [rb] row-sum accumulators (denominator)
#pragma unroll
    for (int rb = 0; rb < 2; ++rb) {
        sacc[rb] = (f32x4v){0.f, 0.f, 0.f, 0.f};
#pragma unroll
        for (int x = 0; x < 4; ++x) acc[rb][x] = (f32x4v){0.f, 0.f, 0.f, 0.f};
    }

    // lane's mask row is its own q-row: qw + rb*16 + l15 ; col base quad*16
    const bf16* mbase = Mr + (size_t)(qw + l15) * 2048 + quad * 16;

    // stage one 64-key tile; 8 chunks over 8 waves: 1 K + 1 V glds16/thread
    auto STAGE = [&](int kts, int bsel) {
        glds16(K + (size_t)(kts + lane) * 64 + wave * 8, &Kls[bsel][wave * 512]);
        glds16(Vg + (size_t)lane * SEQ + kts + wave * 8, &Vls[bsel][wave * 512]);
    };

    STAGE(0, 0);
    __syncthreads();  // drains vmcnt -> buf0 ready for all waves

    for (int kt = 0; kt < SEQ; kt += 64) {
        const int cur = (kt >> 6) & 1;
        // issue next tile's staging first: latency hides under this tile's work
        if (kt + 64 < SEQ) STAGE(kt + 64, cur ^ 1);

        // mask bias for this tile: per rb, 16 contiguous bf16 = 2 x 16B loads
        bf16x8 mv[2][2];
#pragma unroll
        for (int rb = 0; rb < 2; ++rb)
#pragma unroll
            for (int h2 = 0; h2 < 2; ++h2)
                mv[rb][h2] = *(const bf16x8*)(mbase + (size_t)(rb * 16) * 2048 +
                                              kt + h2 * 8);

        const bf16* Kb = &Kls[cur][0];
        const bf16* Vb = &Vls[cur][0];

        // K frags (A operand of swapped QK^T)
        bf16x8 ak[4][2];
#pragma unroll
        for (int n16 = 0; n16 < 4; ++n16)
#pragma unroll
            for (int kk = 0; kk < 2; ++kk)
                ak[n16][kk] = *(const bf16x8*)(&Kb[((kk * 4 + quad) * 64 + n16 * 16 + l15) * 8]);

        // QK^T seeded with mask -> exp2 -> in-register PV A-frags
        bf16x8 pa[2][2];  // [rb][g], elem j=nlow*4+reg <-> k=16*(2g+nlow)+4quad+reg
#pragma unroll
        for (int rb = 0; rb < 2; ++rb) {
            f32x4v sv[4];
#pragma unroll
            for (int n16 = 0; n16 < 4; ++n16) {
                f32x4v s;
#pragma unroll
                for (int reg = 0; reg < 4; ++reg)
                    s[reg] = (float)mv[rb][n16 >> 1][(n16 & 1) * 4 + reg];
                sv[n16] = s;
            }
            __builtin_amdgcn_s_setprio(1);
#pragma unroll
            for (int n16 = 0; n16 < 4; ++n16) {
                sv[n16] = MFMA16(ak[n16][0], aq[rb][0], sv[n16]);  // S[k][q], q=l15
                sv[n16] = MFMA16(ak[n16][1], aq[rb][1], sv[n16]);
            }
            __builtin_amdgcn_s_setprio(0);
#pragma unroll
            for (int n16 = 0; n16 < 4; ++n16)
#pragma unroll
                for (int reg = 0; reg < 4; ++reg) {
                    const float e = exp2f(sv[n16][reg]);
                    pa[rb][n16 >> 1][(n16 & 1) * 4 + reg] = (bf16)e;
                }
        }

        __builtin_amdgcn_s_setprio(1);
        // row sums: sacc[rb][reg] += sum_k P[q][k]  (every column identical)
#pragma unroll
        for (int rb = 0; rb < 2; ++rb) {
            sacc[rb] = MFMA16(pa[rb][0], ones, sacc[rb]);
            sacc[rb] = MFMA16(pa[rb][1], ones, sacc[rb]);
        }
        // O += P V  (V staged with the SAME k-permutation -> axes agree)
#pragma unroll
        for (int nt = 0; nt < 4; ++nt) {
            const bf16x8 bv0 = *(const bf16x8*)(&Vb[((quad * 2 + 0) * 64 + nt * 16 + l15) * 8]);
            const bf16x8 bv1 = *(const bf16x8*)(&Vb[((quad * 2 + 1) * 64 + nt * 16 + l15) * 8]);
#pragma unroll
            for (int rb = 0; rb < 2; ++rb) {
                acc[rb][nt] = MFMA16(pa[rb][0], bv0, acc[rb][nt]);
                acc[rb][nt] = MFMA16(pa[rb][1], bv1, acc[rb][nt]);
            }
        }
        __builtin_amdgcn_s_setprio(0);

        // one barrier per tile: all waves done reading buf[cur]; the vmcnt(0)
        // drain here covers STAGE(kt+64) issued a full compute-phase ago.
        __syncthreads();
    }

    // normalize and write X row-major bf16 [B*S][D_MODEL]
    const int b = bh >> 4, h = bh & 15;
#pragma unroll
    for (int rb = 0; rb < 2; ++rb) {
        float rinv[4];
#pragma unroll
        for (int reg = 0; reg < 4; ++reg) rinv[reg] = 1.0f / sacc[rb][reg];
#pragma unroll
        for (int nt = 0; nt < 4; ++nt)
#pragma unroll
            for (int reg = 0; reg < 4; ++reg) {
                const int sg = qw + rb * 16 + quad * 4 + reg;
                Xout[(size_t)(b * SEQ + sg) * D_MODEL + h * 64 + nt * 16 + l15] =
                    (bf16)(acc[rb][nt][reg] * rinv[reg]);
            }
    }
}

extern "C" void kernel_launch(void* const* d_in, const int* in_sizes, int n_in,
                              void* d_out, int out_size, void* d_ws, size_t ws_size,
                              hipStream_t stream) {
    const float* q    = (const float*)d_in[0];
    const float* k    = (const float*)d_in[1];
    const float* v    = (const float*)d_in[2];
    const int*   mask = (const int*)d_in[3];
    const float* Wq   = (const float*)d_in[4];
    const float* bq   = (const float*)d_in[5];
    const float* Wk   = (const float*)d_in[6];
    const float* bk   = (const float*)d_in[7];
    const float* Wv   = (const float*)d_in[8];
    const float* bv   = (const float*)d_in[9];
    const float* Wo   = (const float*)d_in[10];
    const float* bo   = (const float*)d_in[11];

    const size_t T = (size_t)BATCH * SEQ * D_MODEL;  // 8,388,608
    const size_t WN = (size_t)D_MODEL * D_MODEL;     // 1,048,576
    char* w = (char*)d_ws;
    bf16* Qh  = (bf16*)w;            w += T * 2;
    bf16* Kh  = (bf16*)w;            w += T * 2;
    bf16* Vt  = (bf16*)w;            w += T * 2;
    bf16* Mr  = (bf16*)w;            w += (size_t)SEQ * SEQ * 2;
    bf16* qb  = (bf16*)w;            w += T * 2;   // reused as X after attn
    bf16* kb  = (bf16*)w;            w += T * 2;
    bf16* vb  = (bf16*)w;            w += T * 2;
    bf16* Wqb = (bf16*)w;            w += WN * 2;
    bf16* Wkb = (bf16*)w;            w += WN * 2;
    bf16* Wvb = (bf16*)w;            w += WN * 2;
    bf16* Wob = (bf16*)w;            w += WN * 2;  // total ~112 MiB

    CvtArgs ca;
    ca.s[0] = q;  ca.d[0] = qb;  ca.n[0] = (int)T;
    ca.s[1] = k;  ca.d[1] = kb;  ca.n[1] = (int)T;
    ca.s[2] = v;  ca.d[2] = vb;  ca.n[2] = (int)T;
    ca.s[3] = Wq; ca.d[3] = Wqb; ca.n[3] = (int)WN;
    ca.s[4] = Wk; ca.d[4] = Wkb; ca.n[4] = (int)WN;
    ca.s[5] = Wv; ca.d[5] = Wvb; ca.n[5] = (int)WN;
    ca.s[6] = Wo; ca.d[6] = Wob; ca.n[6] = (int)WN;
    ca.mask = mask;
    ca.Mr   = Mr;

    cvt8<<<dim3(4096, 8), 256, 0, stream>>>(ca);

    G3 g3;
    g3.A[0] = qb;  g3.W[0] = Wqb; g3.bias[0] = bq; g3.out[0] = Qh;
    g3.A[1] = kb;  g3.W[1] = Wkb; g3.bias[1] = bk; g3.out[1] = Kh;
    g3.A[2] = vb;  g3.W[2] = Wvb; g3.bias[2] = bv; g3.out[2] = Vt;
    gemm_qkv<<<dim3(512, 3), 256, 0, stream>>>(g3);

    attn_kernel<<<dim3(BATCH * NH, SEQ / 256), 512, 0, stream>>>(Qh, Kh, Vt, Mr, qb);

    gemm_o<<<dim3(512), 256, 0, stream>>>(qb, Wob, bo, (float*)d_out);
}

// Round 9
// 386.257 us; speedup vs baseline: 1.1433x; 1.1433x over previous
//
#include <hip/hip_runtime.h>
#include <hip/hip_bf16.h>

typedef __bf16 bf16;
typedef __bf16 bf16x8 __attribute__((ext_vector_type(8)));
typedef __bf16 bf16x4 __attribute__((ext_vector_type(4)));
typedef float  f32x4v __attribute__((ext_vector_type(4)));

#define MFMA16(a, b, c) __builtin_amdgcn_mfma_f32_16x16x32_bf16((a), (b), (c), 0, 0, 0)

static constexpr int D_MODEL = 1024;
static constexpr int NH      = 16;
static constexpr int DK      = 64;
static constexpr int BATCH   = 4;
static constexpr int SEQ     = 2048;
static constexpr float CLOG  = 0.125f * 1.4426950408889634f;  // 1/sqrt(dk) * log2(e)

// async global->LDS, 16B per lane; LDS dest = wave-uniform base + lane*16
__device__ __forceinline__ void glds16(const void* g, void* l) {
    __builtin_amdgcn_global_load_lds((const __attribute__((address_space(1))) void*)g,
                                     (__attribute__((address_space(3))) void*)l, 16, 0, 0);
}

// ---------------------------------------------------------------------------
// fp32 -> bf16 bulk convert, 7 tensors + mask prep in ONE launch (y selects).
// Mask slice (y==7): int32 [S][S] -> bf16 ADDITIVE bias, columns permuted
// within each 64-group to pos(s) = quad(s)*16 + n(s)*4 + r(s) where
// s = 16n + 4quad + r (matches the attn PV k-axis).  bias = 0 or -16384
// (exact in bf16; exp2 underflows to exactly 0, matching the -1e9 ref).
// ---------------------------------------------------------------------------
struct CvtArgs {
    const float* s[7];
    bf16* d[7];
    int n[7];
    const int* mask;
    bf16* Mr;
};

__global__ __launch_bounds__(256) void cvt8(CvtArgs a) {
    const int which = blockIdx.y;
    const int i = (blockIdx.x * 256 + threadIdx.x) * 8;
    if (which == 7) {  // mask prep, 8 outputs/thread (same row & 64-group)
        if (i >= SEQ * SEQ) return;
        const int row = i >> 11, j0 = i & 2047;
        const int g = j0 >> 6;
        bf16x8 o;
#pragma unroll
        for (int t = 0; t < 8; ++t) {
            const int idx = (j0 + t) & 63;  // = pos; invert the permutation
            const int incol =
                (g << 6) + (((idx >> 2) & 3) << 4) + ((idx >> 4) << 2) + (idx & 3);
            o[t] = a.mask[row * 2048 + incol] ? (bf16)0.0f : (bf16)-16384.0f;
        }
        *(bf16x8*)(a.Mr + i) = o;
        return;
    }
    if (i >= a.n[which]) return;
    const float4 v0 = *(const float4*)(a.s[which] + i);
    const float4 v1 = *(const float4*)(a.s[which] + i + 4);
    bf16x8 o = {(bf16)v0.x, (bf16)v0.y, (bf16)v0.z, (bf16)v0.w,
                (bf16)v1.x, (bf16)v1.y, (bf16)v1.z, (bf16)v1.w};
    *(bf16x8*)(a.d[which] + i) = o;
}

// ---------------------------------------------------------------------------
// Fused Q/K/V projection GEMMs: one launch, blockIdx.y selects tensor.
// C = (A @ W^T + bias) * scale.  128x128 tile, BK=32, glds16 staging,
// SINGLE-BARRIER DOUBLE-BUFFERED K-loop (round-9): stage k+1 into buf^1,
// compute buf, one __syncthreads per K-step — the vmcnt(0) drain at the
// barrier covers loads issued a full compute phase earlier (the 2-barrier
// version exposes the full drain at 2 blocks/CU).  4 waves of 64x64.
// XCD panel-clustered swizzle on x (same m-panel -> same XCD L2).
// y=0: Q, scale=CLOG (pre-scales scores so attn exp2 needs no fma);
// y=1: K, scale=1    — both stored head-major bf16 [b][h][s][dk];
// y=2: V, stored as V^T [b][h][dk][s] with s permuted per 64-group:
//      pos(s) = quad*16 + n*4 + r  (matches mask / attn PV k-axis).
// ---------------------------------------------------------------------------
struct G3 {
    const bf16* A[3];
    const bf16* W[3];
    const float* bias[3];
    bf16* out[3];
};

__global__ __launch_bounds__(256) void gemm_qkv(G3 g) {
    __shared__ bf16 Als[2][4096];  // dbuf x (128 rows x 32 bf16 packed)
    __shared__ bf16 Bls[2][4096];

    const int which = blockIdx.y;
    const bf16* __restrict__ A   = g.A[which];
    const bf16* __restrict__ W   = g.W[which];
    const float* __restrict__ bias = g.bias[which];
    const float scale = (which == 0) ? CLOG : 1.0f;

    const int tid  = threadIdx.x;
    const int wave = tid >> 6;
    const int lane = tid & 63;
    const int l15  = lane & 15;
    const int quad = lane >> 4;
    // XCD swizzle: L bits [2:0]=a, [5:3]=b, [8:6]=c.  m-tile = a + 8c (64),
    // n-tile = b (8).  Same m-tile => same a => same XCD (hw: linear%8;
    // grid x-size 512 is a multiple of 8 so each y-slice maps identically).
    const int L    = blockIdx.x;
    const int m0   = ((L & 7) | ((L >> 6) << 3)) * 128;
    const int n0   = ((L >> 3) & 7) * 128;
    const int wm   = (wave >> 1) * 64;
    const int wn   = (wave & 1) * 64;

    f32x4v acc[4][4];
#pragma unroll
    for (int i = 0; i < 4; ++i)
#pragma unroll
        for (int j = 0; j < 4; ++j) acc[i][j] = (f32x4v){0.f, 0.f, 0.f, 0.f};

    // staging map: slot = p*256 + wave*64 + lane; row = slot>>2, chunk = slot&3
    const int r_a    = wave * 16 + (lane >> 2);
    const int c_a    = (lane & 3) * 8;
    const int ldsoff = wave * 512;  // elements; + p*2048

    auto STAGE = [&](int k0, int bsel) {
#pragma unroll
        for (int p = 0; p < 2; ++p) {
            const int row = p * 64 + r_a;
            glds16(A + (size_t)(m0 + row) * 1024 + k0 + c_a, &Als[bsel][p * 2048 + ldsoff]);
            glds16(W + (size_t)(n0 + row) * 1024 + k0 + c_a, &Bls[bsel][p * 2048 + ldsoff]);
        }
    };

    STAGE(0, 0);
    __syncthreads();  // buf0 ready

    for (int k0 = 0; k0 < 1024; k0 += 32) {
        const int cur = (k0 >> 5) & 1;
        if (k0 + 32 < 1024) STAGE(k0 + 32, cur ^ 1);

        bf16x8 af[4], bfr[4];
#pragma unroll
        for (int i = 0; i < 4; ++i)
            af[i] = *(const bf16x8*)(&Als[cur][(wm + i * 16 + l15) * 32 + quad * 8]);
#pragma unroll
        for (int j = 0; j < 4; ++j)
            bfr[j] = *(const bf16x8*)(&Bls[cur][(wn + j * 16 + l15) * 32 + quad * 8]);
#pragma unroll
        for (int i = 0; i < 4; ++i)
#pragma unroll
            for (int j = 0; j < 4; ++j) acc[i][j] = MFMA16(af[i], bfr[j], acc[i][j]);

        // one barrier/iter: everyone done reading buf[cur]; drains the vmcnt
        // for STAGE(k0+32) issued above (covered by the 16 MFMAs).
        __syncthreads();
    }

    // epilogue: C/D layout col = lane&15, row = quad*4 + reg
    bf16* out = g.out[which];
#pragma unroll
    for (int j = 0; j < 4; ++j) {
        const int col = n0 + wn + j * 16 + l15;
        const float bs_s = bias[col] * scale;
        const int h = col >> 6, dk = col & 63;
        if (which == 2) {
            // V^T: logical s-offset o = i*16 + quad*4 + reg -> pos = quad*16+i*4+reg
            // so for fixed i the 4 reg-values are contiguous: bf16x4 store.
            const int sg = m0 + wm;               // 64-aligned
            const int bb = sg >> 11, sb = sg & 2047;
            const size_t rowbase = ((size_t)((bb * NH + h) * 64 + dk)) * SEQ + sb;
#pragma unroll
            for (int i = 0; i < 4; ++i) {
                bf16x4 v = {(bf16)(acc[i][j][0] + bs_s), (bf16)(acc[i][j][1] + bs_s),
                            (bf16)(acc[i][j][2] + bs_s), (bf16)(acc[i][j][3] + bs_s)};
                *(bf16x4*)(&out[rowbase + quad * 16 + i * 4]) = v;
            }
        } else {  // Q/K head-major, optionally pre-scaled
#pragma unroll
            for (int i = 0; i < 4; ++i) {
                const int r4 = m0 + wm + i * 16 + quad * 4;
                const int b = r4 >> 11, sb = r4 & 2047;
#pragma unroll
                for (int reg = 0; reg < 4; ++reg)
                    out[((size_t)(b * NH + h) * SEQ + sb + reg) * 64 + dk] =
                        (bf16)fmaf(acc[i][j][reg], scale, bs_s);
            }
        }
    }
}

// ---------------------------------------------------------------------------
// Final output GEMM: fp32 out = A @ Wo^T + bo.  Same dbuf structure.
// ---------------------------------------------------------------------------
__global__ __launch_bounds__(256) void gemm_o(const bf16* __restrict__ A,
                                              const bf16* __restrict__ W,
                                              const float* __restrict__ bias,
                                              float* __restrict__ out) {
    __shared__ bf16 Als[2][4096];
    __shared__ bf16 Bls[2][4096];

    const int tid  = threadIdx.x;
    const int wave = tid >> 6;
    const int lane = tid & 63;
    const int l15  = lane & 15;
    const int quad = lane >> 4;
    const int L    = blockIdx.x;
    const int m0   = ((L & 7) | ((L >> 6) << 3)) * 128;
    const int n0   = ((L >> 3) & 7) * 128;
    const int wm   = (wave >> 1) * 64;
    const int wn   = (wave & 1) * 64;

    f32x4v acc[4][4];
#pragma unroll
    for (int i = 0; i < 4; ++i)
#pragma unroll
        for (int j = 0; j < 4; ++j) acc[i][j] = (f32x4v){0.f, 0.f, 0.f, 0.f};

    const int r_a    = wave * 16 + (lane >> 2);
    const int c_a    = (lane & 3) * 8;
    const int ldsoff = wave * 512;

    auto STAGE = [&](int k0, int bsel) {
#pragma unroll
        for (int p = 0; p < 2; ++p) {
            const int row = p * 64 + r_a;
            glds16(A + (size_t)(m0 + row) * 1024 + k0 + c_a, &Als[bsel][p * 2048 + ldsoff]);
            glds16(W + (size_t)(n0 + row) * 1024 + k0 + c_a, &Bls[bsel][p * 2048 + ldsoff]);
        }
    };

    STAGE(0, 0);
    __syncthreads();

    for (int k0 = 0; k0 < 1024; k0 += 32) {
        const int cur = (k0 >> 5) & 1;
        if (k0 + 32 < 1024) STAGE(k0 + 32, cur ^ 1);

        bf16x8 af[4], bfr[4];
#pragma unroll
        for (int i = 0; i < 4; ++i)
            af[i] = *(const bf16x8*)(&Als[cur][(wm + i * 16 + l15) * 32 + quad * 8]);
#pragma unroll
        for (int j = 0; j < 4; ++j)
            bfr[j] = *(const bf16x8*)(&Bls[cur][(wn + j * 16 + l15) * 32 + quad * 8]);
#pragma unroll
        for (int i = 0; i < 4; ++i)
#pragma unroll
            for (int j = 0; j < 4; ++j) acc[i][j] = MFMA16(af[i], bfr[j], acc[i][j]);

        __syncthreads();
    }

#pragma unroll
    for (int j = 0; j < 4; ++j) {
        const int col = n0 + wn + j * 16 + l15;
        const float bs = bias[col];
#pragma unroll
        for (int i = 0; i < 4; ++i) {
            const int r4 = m0 + wm + i * 16 + quad * 4;
#pragma unroll
            for (int reg = 0; reg < 4; ++reg)
                out[(size_t)(r4 + reg) * 1024 + col] = acc[i][j][reg] + bs;
        }
    }
}

// ---------------------------------------------------------------------------
// Flash attention (ROUND-5 VERSION, reverted verbatim — measured ~139 µs,
// VGPR 108; the 8-wave rb=2 variants of rounds 6-8 all provoked pathological
// register allocation: either scratch spills or per-tile global re-fetch).
//
// Fixed-max softmax.  Q PRE-SCALED by CLOG; QK^T accumulator SEEDED with the
// bf16 mask bias (0/-16384): e = exp2(sv) directly.  Masked terms are
// exactly 0 (underflow), matching the -1e9 ref.
// SWAPPED QK^T: mfma(K, Q) puts q = l15 -> each lane's scores belong to its
// own q-row = the PV A-frag layout; P never touches LDS.  The induced
// k-permutation pos(s)=quad*16+n*4+r is baked into V^T and the mask.
// Single-barrier double-buffered staging (stage t+1, compute t).
// Row sums via ones-MFMA.  VGPR ~108 (<=128 cliff).
// ---------------------------------------------------------------------------
__global__ __launch_bounds__(256, 2) void attn_kernel(const bf16* __restrict__ Qh,
                                                      const bf16* __restrict__ Kh,
                                                      const bf16* __restrict__ Vtg,
                                                      const bf16* __restrict__ Mr,
                                                      bf16* __restrict__ Xout) {
    __shared__ bf16 Kls[2][4096];    // per buf: 8 chunks x 64 keys x 8 bf16
    __shared__ bf16 Vls[2][4096];    // per buf: 8 chunks x 64 d    x 8 bf16

    const int tid  = threadIdx.x;
    const int wave = tid >> 6;
    const int lane = tid & 63;
    const int l15  = lane & 15;
    const int quad = lane >> 4;
    const int bh   = blockIdx.x;
    const int q0   = blockIdx.y * 256;

    const size_t base = (size_t)bh * SEQ * DK;
    const bf16* Q  = Qh + base;
    const bf16* K  = Kh + base;
    const bf16* Vg = Vtg + base;  // [64][SEQ], s permuted per 64-group

    const int qw = q0 + wave * 64;
    bf16x8 aq[4][2];
#pragma unroll
    for (int rb = 0; rb < 4; ++rb)
#pragma unroll
        for (int kk = 0; kk < 2; ++kk)
            aq[rb][kk] = *(const bf16x8*)(Q + (size_t)(qw + rb * 16 + l15) * 64 +
                                          kk * 32 + quad * 8);

    bf16x8 ones;
#pragma unroll
    for (int t = 0; t < 8; ++t) ones[t] = (bf16)1.0f;

    f32x4v acc[4][4];  // [rb][nt] PV accumulators
    f32x4v sacc[4];    // [rb] row-sum accumulators (denominator)
#pragma unroll
    for (int rb = 0; rb < 4; ++rb) {
        sacc[rb] = (f32x4v){0.f, 0.f, 0.f, 0.f};
#pragma unroll
        for (int x = 0; x < 4; ++x) acc[rb][x] = (f32x4v){0.f, 0.f, 0.f, 0.f};
    }

    // lane's mask row is its own q-row: qw + rb*16 + l15 ; col base quad*16
    const bf16* mbase = Mr + (size_t)(qw + l15) * 2048 + quad * 16;

    // stage one 64-key tile (K rows + permuted V^T cols) into buffer bsel
    auto STAGE = [&](int kts, int bsel) {
#pragma unroll
        for (int p = 0; p < 2; ++p) {
            const int kc = wave * 2 + p;
            glds16(K + (size_t)(kts + lane) * 64 + kc * 8, &Kls[bsel][kc * 512]);
            glds16(Vg + (size_t)lane * SEQ + kts + kc * 8, &Vls[bsel][kc * 512]);
        }
    };

    STAGE(0, 0);
    __syncthreads();  // drains vmcnt -> buf0 ready for all waves

    for (int kt = 0; kt < SEQ; kt += 64) {
        const int cur = (kt >> 6) & 1;
        // issue next tile's staging first: latency hides under this tile's work
        if (kt + 64 < SEQ) STAGE(kt + 64, cur ^ 1);

        // mask bias for this tile: per rb, 16 contiguous bf16 = 2 x 16B loads
        bf16x8 mv[4][2];
#pragma unroll
        for (int rb = 0; rb < 4; ++rb)
#pragma unroll
            for (int h2 = 0; h2 < 2; ++h2)
                mv[rb][h2] = *(const bf16x8*)(mbase + (size_t)(rb * 16) * 2048 +
                                              kt + h2 * 8);

        const bf16* Kb = &Kls[cur][0];
        const bf16* Vb = &Vls[cur][0];

        // K frags (A operand of swapped QK^T)
        bf16x8 ak[4][2];
#pragma unroll
        for (int n16 = 0; n16 < 4; ++n16)
#pragma unroll
            for (int kk = 0; kk < 2; ++kk)
                ak[n16][kk] = *(const bf16x8*)(&Kb[((kk * 4 + quad) * 64 + n16 * 16 + l15) * 8]);

        // QK^T seeded with mask -> exp2 -> in-register PV A-frags
        bf16x8 pa[4][2];  // [rb][g], elem j=nlow*4+reg <-> k=16*(2g+nlow)+4quad+reg
#pragma unroll
        for (int rb = 0; rb < 4; ++rb) {
            f32x4v sv[4];
#pragma unroll
            for (int n16 = 0; n16 < 4; ++n16) {
                f32x4v s;
#pragma unroll
                for (int reg = 0; reg < 4; ++reg)
                    s[reg] = (float)mv[rb][n16 >> 1][(n16 & 1) * 4 + reg];
                sv[n16] = s;
            }
            __builtin_amdgcn_s_setprio(1);
#pragma unroll
            for (int n16 = 0; n16 < 4; ++n16) {
                sv[n16] = MFMA16(ak[n16][0], aq[rb][0], sv[n16]);  // S[k][q], q=l15
                sv[n16] = MFMA16(ak[n16][1], aq[rb][1], sv[n16]);
            }
            __builtin_amdgcn_s_setprio(0);
#pragma unroll
            for (int n16 = 0; n16 < 4; ++n16)
#pragma unroll
                for (int reg = 0; reg < 4; ++reg) {
                    const float e = exp2f(sv[n16][reg]);
                    pa[rb][n16 >> 1][(n16 & 1) * 4 + reg] = (bf16)e;
                }
        }

        __builtin_amdgcn_s_setprio(1);
        // row sums: sacc[rb][reg] += sum_k P[q][k]  (every column identical)
#pragma unroll
        for (int rb = 0; rb < 4; ++rb) {
            sacc[rb] = MFMA16(pa[rb][0], ones, sacc[rb]);
            sacc[rb] = MFMA16(pa[rb][1], ones, sacc[rb]);
        }
        // O += P V  (V staged with the SAME k-permutation -> axes agree)
#pragma unroll
        for (int nt = 0; nt < 4; ++nt) {
            const bf16x8 bv0 = *(const bf16x8*)(&Vb[((quad * 2 + 0) * 64 + nt * 16 + l15) * 8]);
            const bf16x8 bv1 = *(const bf16x8*)(&Vb[((quad * 2 + 1) * 64 + nt * 16 + l15) * 8]);
#pragma unroll
            for (int rb = 0; rb < 4; ++rb) {
                acc[rb][nt] = MFMA16(pa[rb][0], bv0, acc[rb][nt]);
                acc[rb][nt] = MFMA16(pa[rb][1], bv1, acc[rb][nt]);
            }
        }
        __builtin_amdgcn_s_setprio(0);

        // one barrier per tile: all waves done reading buf[cur]; the vmcnt(0)
        // drain here covers STAGE(kt+64) issued a full compute-phase ago.
        __syncthreads();
    }

    // normalize and write X row-major bf16 [B*S][D_MODEL]
    const int b = bh >> 4, h = bh & 15;
#pragma unroll
    for (int rb = 0; rb < 4; ++rb) {
        float rinv[4];
#pragma unroll
        for (int reg = 0; reg < 4; ++reg) rinv[reg] = 1.0f / sacc[rb][reg];
#pragma unroll
        for (int nt = 0; nt < 4; ++nt)
#pragma unroll
            for (int reg = 0; reg < 4; ++reg) {
                const int sg = qw + rb * 16 + quad * 4 + reg;
                Xout[(size_t)(b * SEQ + sg) * D_MODEL + h * 64 + nt * 16 + l15] =
                    (bf16)(acc[rb][nt][reg] * rinv[reg]);
            }
    }
}

extern "C" void kernel_launch(void* const* d_in, const int* in_sizes, int n_in,
                              void* d_out, int out_size, void* d_ws, size_t ws_size,
                              hipStream_t stream) {
    const float* q    = (const float*)d_in[0];
    const float* k    = (const float*)d_in[1];
    const float* v    = (const float*)d_in[2];
    const int*   mask = (const int*)d_in[3];
    const float* Wq   = (const float*)d_in[4];
    const float* bq   = (const float*)d_in[5];
    const float* Wk   = (const float*)d_in[6];
    const float* bk   = (const float*)d_in[7];
    const float* Wv   = (const float*)d_in[8];
    const float* bv   = (const float*)d_in[9];
    const float* Wo   = (const float*)d_in[10];
    const float* bo   = (const float*)d_in[11];

    const size_t T = (size_t)BATCH * SEQ * D_MODEL;  // 8,388,608
    const size_t WN = (size_t)D_MODEL * D_MODEL;     // 1,048,576
    char* w = (char*)d_ws;
    bf16* Qh  = (bf16*)w;            w += T * 2;
    bf16* Kh  = (bf16*)w;            w += T * 2;
    bf16* Vt  = (bf16*)w;            w += T * 2;
    bf16* Mr  = (bf16*)w;            w += (size_t)SEQ * SEQ * 2;
    bf16* qb  = (bf16*)w;            w += T * 2;   // reused as X after attn
    bf16* kb  = (bf16*)w;            w += T * 2;
    bf16* vb  = (bf16*)w;            w += T * 2;
    bf16* Wqb = (bf16*)w;            w += WN * 2;
    bf16* Wkb = (bf16*)w;            w += WN * 2;
    bf16* Wvb = (bf16*)w;            w += WN * 2;
    bf16* Wob = (bf16*)w;            w += WN * 2;  // total ~112 MiB

    CvtArgs ca;
    ca.s[0] = q;  ca.d[0] = qb;  ca.n[0] = (int)T;
    ca.s[1] = k;  ca.d[1] = kb;  ca.n[1] = (int)T;
    ca.s[2] = v;  ca.d[2] = vb;  ca.n[2] = (int)T;
    ca.s[3] = Wq; ca.d[3] = Wqb; ca.n[3] = (int)WN;
    ca.s[4] = Wk; ca.d[4] = Wkb; ca.n[4] = (int)WN;
    ca.s[5] = Wv; ca.d[5] = Wvb; ca.n[5] = (int)WN;
    ca.s[6] = Wo; ca.d[6] = Wob; ca.n[6] = (int)WN;
    ca.mask = mask;
    ca.Mr   = Mr;

    cvt8<<<dim3(4096, 8), 256, 0, stream>>>(ca);

    G3 g3;
    g3.A[0] = qb;  g3.W[0] = Wqb; g3.bias[0] = bq; g3.out[0] = Qh;
    g3.A[1] = kb;  g3.W[1] = Wkb; g3.bias[1] = bk; g3.out[1] = Kh;
    g3.A[2] = vb;  g3.W[2] = Wvb; g3.bias[2] = bv; g3.out[2] = Vt;
    gemm_qkv<<<dim3(512, 3), 256, 0, stream>>>(g3);

    attn_kernel<<<dim3(BATCH * NH, SEQ / 256), 256, 0, stream>>>(Qh, Kh, Vt, Mr, qb);

    gemm_o<<<dim3(512), 256, 0, stream>>>(qb, Wob, bo, (float*)d_out);
}